// Round 6
// baseline (3834.816 us; speedup 1.0000x reference)
//
#include <hip/hip_runtime.h>
#include <hip/hip_bf16.h>

typedef __hip_bfloat16 bf16;
typedef __bf16 bf16x8 __attribute__((ext_vector_type(8)));
typedef float f32x4 __attribute__((ext_vector_type(4)));

#define ROWS   32
#define HID    1024
#define PATH   256
#define NSTEP  50
#define P      1032   // LDS pitch (bf16): 1024 + 8
#define SMEM_BYTES (2 * ROWS * P * 2)   // inp + th, bf16

__device__ __forceinline__ f32x4 mfma16(bf16x8 a, bf16x8 b, f32x4 c) {
    return __builtin_amdgcn_mfma_f32_16x16x32_bf16(a, b, c, 0, 0, 0);
}

__device__ __forceinline__ float tanh_fast(float x) {
    float e = __expf(2.0f * x);
    return 1.0f - 2.0f / (e + 1.0f);
}

__device__ __forceinline__ bf16x8 ldcvt8(const float* __restrict__ p) {
    f32x4 lo = *(const f32x4*)p;
    f32x4 hi = *(const f32x4*)(p + 4);
    bf16x8 r;
    #pragma unroll
    for (int j = 0; j < 4; j++) { r[j] = (__bf16)lo[j]; r[4 + j] = (__bf16)hi[j]; }
    return r;
}

// ---- pack f32 W[K][N] into bf16 MFMA B-fragment-linear layout ----
__global__ void pack_frag(const float* __restrict__ src, bf16* __restrict__ dst, int N) {
    int kb = blockIdx.x, nb = blockIdx.y, l = threadIdx.x;
    int lm = l & 15, lq = l >> 4;
    bf16x8 v;
    #pragma unroll
    for (int j = 0; j < 8; j++)
        v[j] = __float2bfloat16(src[(size_t)(kb * 32 + lq * 8 + j) * N + nb * 16 + lm]);
    *(bf16x8*)(dst + ((size_t)(kb * gridDim.y + nb) * 64 + l) * 8) = v;
}

// ---- 16-row x 128-col GEMM slice, rotated K-loop ----
// Wave covers N-tiles nb = cg*8 .. cg*8+7 of a 1024-col packed weight; A rows = mt-tile.
// Paired waves (same cg, different mt) read the SAME weight stream -> L1 reuse.
template<int KB>
__device__ __forceinline__ void gemm8p(const bf16* __restrict__ lds,
                                       const bf16* __restrict__ Wp,
                                       int cg, int mt, int lane, int rot,
                                       f32x4 (&acc)[8]) {
    const int lm = lane & 15, lq = lane >> 4;
    #pragma unroll 2
    for (int kb = 0; kb < KB; kb++) {
        int kbr = kb + rot; if (kbr >= KB) kbr -= KB;    // wg-uniform scalar
        const bf16* wp = Wp + (((size_t)kbr * 64 + cg * 8) * 64 + lane) * 8;
        bf16x8 a = *(const bf16x8*)(lds + (mt * 16 + lm) * P + kbr * 32 + lq * 8);
        bf16x8 w[4];
        #pragma unroll
        for (int nt = 0; nt < 4; nt++) w[nt] = *(const bf16x8*)(wp + nt * 512);
        #pragma unroll
        for (int nt = 0; nt < 4; nt++) acc[nt] = mfma16(a, w[nt], acc[nt]);
        #pragma unroll
        for (int nt = 0; nt < 4; nt++) w[nt] = *(const bf16x8*)(wp + (4 + nt) * 512);
        #pragma unroll
        for (int nt = 0; nt < 4; nt++) acc[4 + nt] = mfma16(a, w[nt], acc[4 + nt]);
    }
}

// ---------------- persistent fused CDE kernel ----------------
// 256 wgs (1/CU), 1024 threads = 16 waves. Wave w: M-tile mt=w>>3 (16 rows),
// col-group cg=w&7 (128 cols). Pairs (w, w+8) share one weight stream via L1.
__global__ __launch_bounds__(1024) void cde_main(
    const float* __restrict__ x0,  const float* __restrict__ b_pe, const float* __restrict__ b_hi,
    const float* __restrict__ b1v, const float* __restrict__ b2v,  const float* __restrict__ b_ro,
    const bf16* __restrict__ WpeP, const bf16* __restrict__ WhiP,
    const bf16* __restrict__ W1zP, const bf16* __restrict__ W1uP,
    const bf16* __restrict__ W2P,  const bf16* __restrict__ WroP,
    float* __restrict__ out)
{
    extern __shared__ bf16 smem[];
    bf16* inp = smem;              // [32][P]  z staging (prologue: g staging)
    bf16* th  = smem + ROWS * P;   // [32][P]

    const int tid  = threadIdx.x;
    const int wave = tid >> 6;     // 0..15
    const int lane = tid & 63;
    const int lm   = lane & 15;
    const int lq   = lane >> 4;
    const int mt   = wave >> 3;    // 0..1   M-tile
    const int cg   = wave & 7;     // 0..7   column group (128 cols)
    const int rot  = (blockIdx.x >> 3) & 31;
    const long row0 = (long)blockIdx.x * ROWS;

    f32x4 z[8];      // z rows mt*16+lq*4+r, cols cg*128+nt*16+lm
    f32x4 c_u[8];    // g @ W1u, same layout
    f32x4 g[2];      // g rows mt-tile, cols cg*32+nt*16+lm (nt=0..1)

    // ---- merged prologue: g = x0@W_pe + b_pe ; z = x0@W_hi + b_hi ----
    #pragma unroll
    for (int nt = 0; nt < 8; nt++) {
        float b = b_hi[cg * 128 + nt * 16 + lm];
        #pragma unroll
        for (int r = 0; r < 4; r++) z[nt][r] = b;
    }
    #pragma unroll
    for (int nt = 0; nt < 2; nt++) {
        float b = b_pe[cg * 32 + nt * 16 + lm];
        #pragma unroll
        for (int r = 0; r < 4; r++) g[nt][r] = b;
    }
    for (int kb = 0; kb < HID / 32; kb++) {
        int kbr = kb + rot; if (kbr >= 32) kbr -= 32;
        bf16x8 a = ldcvt8(x0 + (row0 + mt * 16 + lm) * HID + kbr * 32 + lq * 8);
        const bf16* wp = WhiP + (((size_t)kbr * 64 + cg * 8) * 64 + lane) * 8;
        #pragma unroll
        for (int nt = 0; nt < 8; nt++) {
            bf16x8 bb = *(const bf16x8*)(wp + nt * 512);
            z[nt] = mfma16(a, bb, z[nt]);
        }
        const bf16* pp = WpeP + (((size_t)kbr * 16 + cg * 2) * 64 + lane) * 8;
        #pragma unroll
        for (int nt = 0; nt < 2; nt++) {
            bf16x8 bb = *(const bf16x8*)(pp + nt * 512);
            g[nt] = mfma16(a, bb, g[nt]);
        }
    }

    // ---- c_u = g @ W1u (once): stage g, then 8 k-blocks ----
    #pragma unroll
    for (int nt = 0; nt < 2; nt++)
        #pragma unroll
        for (int r = 0; r < 4; r++)
            inp[(mt * 16 + lq * 4 + r) * P + cg * 32 + nt * 16 + lm] = __float2bfloat16(g[nt][r]);
    __syncthreads();
    #pragma unroll
    for (int nt = 0; nt < 8; nt++)
        #pragma unroll
        for (int r = 0; r < 4; r++) c_u[nt][r] = 0.0f;
    for (int kb = 0; kb < PATH / 32; kb++) {
        const bf16* wp = W1uP + (((size_t)kb * 64 + cg * 8) * 64 + lane) * 8;
        bf16x8 a = *(const bf16x8*)(inp + (mt * 16 + lm) * P + kb * 32 + lq * 8);
        #pragma unroll
        for (int nt = 0; nt < 8; nt++) {
            bf16x8 bb = *(const bf16x8*)(wp + nt * 512);
            c_u[nt] = mfma16(a, bb, c_u[nt]);
        }
    }
    __syncthreads();

    // hoist biases
    float b1r[8], b2r[8];
    #pragma unroll
    for (int nt = 0; nt < 8; nt++) {
        b1r[nt] = b1v[cg * 128 + nt * 16 + lm];
        b2r[nt] = b2v[cg * 128 + nt * 16 + lm];
    }

    const float DT = 1.0f / (float)NSTEP;

    // ---- 50 fused steps ----
    for (int s = 0; s < NSTEP; s++) {
        float t = DT * (float)(s + 1);

        // A-phase: refresh bf16 z staging
        #pragma unroll
        for (int nt = 0; nt < 8; nt++)
            #pragma unroll
            for (int r = 0; r < 4; r++)
                inp[(mt * 16 + lq * 4 + r) * P + cg * 128 + nt * 16 + lm] =
                    __float2bfloat16(z[nt][r]);
        __syncthreads();

        // B-phase: h = tanh(z @ W1z + t*c_u + b1) -> th
        {
            f32x4 acc[8];
            #pragma unroll
            for (int nt = 0; nt < 8; nt++)
                #pragma unroll
                for (int r = 0; r < 4; r++)
                    acc[nt][r] = fmaf(t, c_u[nt][r], b1r[nt]);
            gemm8p<HID / 32>(inp, W1zP, cg, mt, lane, rot, acc);
            #pragma unroll
            for (int nt = 0; nt < 8; nt++)
                #pragma unroll
                for (int r = 0; r < 4; r++)
                    th[(mt * 16 + lq * 4 + r) * P + cg * 128 + nt * 16 + lm] =
                        __float2bfloat16(tanh_fast(acc[nt][r]));
        }
        __syncthreads();

        // C-phase: dz = th @ W2 + b2 ; z += dt*dz
        {
            f32x4 acc[8];
            #pragma unroll
            for (int nt = 0; nt < 8; nt++)
                #pragma unroll
                for (int r = 0; r < 4; r++) acc[nt][r] = b2r[nt];
            gemm8p<HID / 32>(th, W2P, cg, mt, lane, rot, acc);
            #pragma unroll
            for (int nt = 0; nt < 8; nt++)
                #pragma unroll
                for (int r = 0; r < 4; r++)
                    z[nt][r] += DT * acc[nt][r];
        }
        // no barrier: th hazards separated by the next A->B barrier (a wave writes th
        // only after that barrier, which all waves reach only after their th reads).
    }

    // ---- epilogue: out = z @ W_ro + b_ro (f32 store) ----
    #pragma unroll
    for (int nt = 0; nt < 8; nt++)
        #pragma unroll
        for (int r = 0; r < 4; r++)
            inp[(mt * 16 + lq * 4 + r) * P + cg * 128 + nt * 16 + lm] =
                __float2bfloat16(z[nt][r]);
    __syncthreads();
    {
        f32x4 acc[8];
        #pragma unroll
        for (int nt = 0; nt < 8; nt++) {
            float b = b_ro[cg * 128 + nt * 16 + lm];
            #pragma unroll
            for (int r = 0; r < 4; r++) acc[nt][r] = b;
        }
        gemm8p<HID / 32>(inp, WroP, cg, mt, lane, rot, acc);
        #pragma unroll
        for (int nt = 0; nt < 8; nt++)
            #pragma unroll
            for (int r = 0; r < 4; r++)
                out[(row0 + mt * 16 + lq * 4 + r) * HID + cg * 128 + nt * 16 + lm] =
                    acc[nt][r];
    }
}

extern "C" void kernel_launch(void* const* d_in, const int* in_sizes, int n_in,
                              void* d_out, int out_size, void* d_ws, size_t ws_size,
                              hipStream_t stream) {
    (void)in_sizes; (void)n_in; (void)out_size; (void)ws_size;
    const float* x0  = (const float*)d_in[0];
    const float* Wpe = (const float*)d_in[1];
    const float* bpe = (const float*)d_in[2];
    const float* Whi = (const float*)d_in[3];
    const float* bhi = (const float*)d_in[4];
    const float* W1  = (const float*)d_in[5];
    const float* b1  = (const float*)d_in[6];
    const float* W2  = (const float*)d_in[7];
    const float* b2  = (const float*)d_in[8];
    const float* Wro = (const float*)d_in[9];
    const float* bro = (const float*)d_in[10];

    bf16* ws   = (bf16*)d_ws;
    bf16* WpeP = ws;                          // 256*1024
    bf16* WhiP = WpeP + 256 * 1024;           // 1024*1024
    bf16* W1zP = WhiP + 1024 * 1024;          // 1024*1024 (W1 rows 0..1023)
    bf16* W1uP = W1zP + 1024 * 1024;          // 256*1024  (W1 rows 1024..1279)
    bf16* W2P  = W1uP + 256 * 1024;           // 1024*1024
    bf16* WroP = W2P  + 1024 * 1024;          // 1024*1024

    hipLaunchKernelGGL(pack_frag, dim3(1024 / 32, 256 / 16), dim3(64), 0, stream, Wpe, WpeP, 256);
    hipLaunchKernelGGL(pack_frag, dim3(1024 / 32, 1024 / 16), dim3(64), 0, stream, Whi, WhiP, 1024);
    hipLaunchKernelGGL(pack_frag, dim3(1024 / 32, 1024 / 16), dim3(64), 0, stream, W1, W1zP, 1024);
    hipLaunchKernelGGL(pack_frag, dim3(256 / 32, 1024 / 16), dim3(64), 0, stream,
                       W1 + (size_t)1024 * 1024, W1uP, 1024);
    hipLaunchKernelGGL(pack_frag, dim3(1024 / 32, 1024 / 16), dim3(64), 0, stream, W2, W2P, 1024);
    hipLaunchKernelGGL(pack_frag, dim3(1024 / 32, 1024 / 16), dim3(64), 0, stream, Wro, WroP, 1024);

    hipFuncSetAttribute((const void*)cde_main,
                        hipFuncAttributeMaxDynamicSharedMemorySize, SMEM_BYTES);
    hipLaunchKernelGGL(cde_main, dim3(8192 / ROWS), dim3(1024), SMEM_BYTES, stream,
                       x0, bpe, bhi, b1, b2, bro, WpeP, WhiP, W1zP, W1uP, W2P, WroP,
                       (float*)d_out);
}